// Round 11
// baseline (530.791 us; speedup 1.0000x reference)
//
#include <hip/hip_runtime.h>
#include <hip/hip_bf16.h>

// ---------------------------------------------------------------------------
// GumbelNeRF fused kernel, round 11: hi-only pass 1 + MFMA-batched exact
// fixup + register diet targeting natural 3 waves/SIMD.
//
// R10 post-mortem: hi-only pass 1 removed 29us of MFMA-pipe time (verified)
// but the fixup's serial latency-bound k-loop (~38K cy per flagged point,
// one wave working while 3 wait) cost ~90us. Fixes:
//  - Fixup = pass-2a-shaped bucketed MFMA, 3-product split (error 2^-21),
//    all flagged points in one <=16-slot batch, in-lane wsig reduce + shfl.
//    ~1-2K cycles, uniform barriers (fcnt block-uniform).
//  - Phase A = R8's transposed wave-private version (32 acc, proven):
//    max AGPR across kernel 64 -> 32; total unified ~= 110 arch + 32 =
//    ~142 < 170 -> HW grants 3 waves/SIMD naturally under (256,2).
//    (Forced (256,3) provably makes the allocator split arch<=84 -> spill.)
//  - LDS stays exactly 47104 (3-block-proven): bookkeeping + fixup scratch
//    overlaid in sRedE AFTER argmax reads, barrier-separated.
// ---------------------------------------------------------------------------

#define NPTS 131072
#define PT 64
#define NTH 256
#define NBLK (NPTS / PT)
#define INV2048 (1.0f / 2048.0f)
#define TAU 0.02f

// ws sections (f16 element offsets) — identical to rounds 2-7
#define WS_ENC_H 0
#define WS_ENC_L 8192
#define WS_SH_H  16384
#define WS_SH_L  147456
#define WS_R1_H  278528

// LDS byte offsets, total 47104
#define OFF_YH   0      // sYh [64][136] f16 = 17408 ; pass2b+: sH [64][68] f32
#define OFF_B    17408  // sPEh[64][72](9216)+sPEl(9216) | sYl[64][136] | sSB[64][168] f16 (21504)
#define OFF_RED  38912  // sRedE [8][4][64] f32 = 8192 ; post-argmax overlay below
#define SMEM_SZ  47104

typedef __attribute__((ext_vector_type(8))) _Float16 f16x8;
typedef __attribute__((ext_vector_type(4))) _Float16 f16x4;
typedef __attribute__((ext_vector_type(4))) float f32x4;

#define MFMA(a, b, c) __builtin_amdgcn_mfma_f32_16x16x32_f16((a), (b), (c), 0, 0, 0)

__device__ __forceinline__ unsigned rotl32(unsigned x, int d) {
  return (x << d) | (x >> (32 - d));
}

// JAX threefry2x32, keys (0,42), counter (0, flat), partitionable fold.
__device__ __forceinline__ float gumbel_for(unsigned flat) {
  const unsigned k0 = 0u, k1 = 42u;
  const unsigned ks2 = k0 ^ k1 ^ 0x1BD11BDAu;
  unsigned x0 = 0u + k0;
  unsigned x1 = flat + k1;
#define TF_RND(r) { x0 += x1; x1 = rotl32(x1, r); x1 ^= x0; }
  TF_RND(13) TF_RND(15) TF_RND(26) TF_RND(6)
  x0 += k1;  x1 += ks2 + 1u;
  TF_RND(17) TF_RND(29) TF_RND(16) TF_RND(24)
  x0 += ks2; x1 += k0 + 2u;
  TF_RND(13) TF_RND(15) TF_RND(26) TF_RND(6)
  x0 += k0;  x1 += k1 + 3u;
  TF_RND(17) TF_RND(29) TF_RND(16) TF_RND(24)
  x0 += k1;  x1 += ks2 + 4u;
  TF_RND(13) TF_RND(15) TF_RND(26) TF_RND(6)
  x0 += ks2; x1 += k0 + 5u;
#undef TF_RND
  unsigned bits = x0 ^ x1;
  float u = __uint_as_float((bits >> 9) | 0x3f800000u) - 1.0f;
  return -logf(-logf(u + 1e-20f) + 1e-20f);
}

__device__ __forceinline__ float softplus_f(float dotv) {
  return fmaxf(dotv, 0.0f) + log1pf(expf(-fabsf(dotv)));
}

// ---------------------------------------------------------------------------
// prep: fp32 weights -> fragment-linear f16 (scaled split) in ws
// ---------------------------------------------------------------------------
__global__ void prep_kernel(const float* __restrict__ W_enc,
                            const float* __restrict__ W_sh,
                            const float* __restrict__ W_r1,
                            _Float16* __restrict__ ws) {
  int idx = blockIdx.x * 256 + threadIdx.x;
  if (idx < 8192) {
    int tile = idx >> 9, r = idx & 511;
    int L = r >> 3, j = r & 7;
    int nt = tile >> 1, kt = tile & 1;
    int k = kt * 32 + (L >> 4) * 8 + j;
    int n = nt * 16 + (L & 15);
    float v = (k < 63) ? W_enc[k * 128 + n] : 0.0f;
    _Float16 h = (_Float16)v;
    ws[WS_ENC_H + idx] = h;
    ws[WS_ENC_L + idx] = (_Float16)((v - (float)h) * 2048.0f);
  } else if (idx < 8192 + 131072) {
    int s = idx - 8192;
    int tile = s >> 9, r = s & 511;
    int L = r >> 3, j = r & 7;
    int e = tile >> 5, nt = (tile >> 2) & 7, kt = tile & 3;
    int k = kt * 32 + (L >> 4) * 8 + j;
    int n = nt * 16 + (L & 15);
    float v = W_sh[e * 16384 + k * 128 + n];
    _Float16 h = (_Float16)v;
    ws[WS_SH_H + s] = h;
    ws[WS_SH_L + s] = (_Float16)((v - (float)h) * 2048.0f);
  } else if (idx < 8192 + 131072 + 81920) {
    int s = idx - (8192 + 131072);
    int tile = s >> 9, r = s & 511;
    int L = r >> 3, j = r & 7;
    int e = tile / 20, rr = tile % 20;
    int nt = rr / 5, kt = rr % 5;
    int k = kt * 32 + (L >> 4) * 8 + j;
    int n = nt * 16 + (L & 15);
    float v = (k < 155) ? W_r1[e * 9920 + k * 64 + n] : 0.0f;
    ws[WS_R1_H + s] = (_Float16)v;
  }
}

// ---------------------------------------------------------------------------
__global__ __launch_bounds__(NTH, 2)
void nerf_moe_kernel(const float* __restrict__ x,
                     const float* __restrict__ b_enc,
                     const float* __restrict__ b_sh,
                     const float* __restrict__ w_sig, const float* __restrict__ b_sig,
                     const float* __restrict__ b_r1,
                     const float* __restrict__ W_r2,  const float* __restrict__ b_r2,
                     const _Float16* __restrict__ wsw,
                     float* __restrict__ out) {
  __shared__ __align__(16) unsigned char smem[SMEM_SZ];
  _Float16* sYh  = (_Float16*)(smem + OFF_YH);
  float*    sH   = (float*)(smem + OFF_YH);
  _Float16* sYl  = (_Float16*)(smem + OFF_B);
  _Float16* sPEh = (_Float16*)(smem + OFF_B);
  _Float16* sPEl = (_Float16*)(smem + OFF_B + 9216);
  _Float16* sSB  = (_Float16*)(smem + OFF_B);
  float*    sRedE = (float*)(smem + OFF_RED);   // [8][4][64] during pass 1
  int*      sBk  = (int*)(smem + OFF_RED);      // post-argmax overlay (ints)
  float*    sFix = (float*)(smem + OFF_RED) + 224;  // [16][8] f32
#define IBID(p)  sBk[(p)]
#define ILIST(s) sBk[64 + (s)]
#define ICNT(e)  sBk[128 + (e)]
#define IOFF(e)  sBk[136 + (e)]
#define FMASK(wv) sBk[144 + (wv)]
#define FCNT     sBk[148]
#define FLIST(i) sBk[160 + (i)]

  const int t  = threadIdx.x;
  const int w  = t >> 6;        // wave id 0..3
  const int L  = t & 63;        // lane
  const int q  = L >> 4;        // quad 0..3
  const int c  = L & 15;
  const int n0 = blockIdx.x * PT;

  // ---- phase 0: xyz positional encoding ----
  for (int idx = t; idx < PT * 64; idx += NTH) {
    int p = idx >> 6, f = idx & 63;
    const float* xr = x + (size_t)(n0 + p) * 6;
    float v;
    if (f < 3)       v = xr[f];
    else if (f < 33) { int g = f - 3;  v = sinf(xr[g % 3] * (float)(1 << (g / 3))); }
    else if (f < 63) { int g = f - 33; v = cosf(xr[g % 3] * (float)(1 << (g / 3))); }
    else             v = 0.0f;
    _Float16 h = (_Float16)v;
    sPEh[p * 72 + f] = h;
    sPEl[p * 72 + f] = (_Float16)((v - (float)h) * 2048.0f);
  }
  __syncthreads();                                   // (1)

  // ---- phase A (transposed, wave-private pt-tiles; 32 acc max) ----
  {
    f16x8 peh[2], pel[2];
    #pragma unroll
    for (int kt = 0; kt < 2; ++kt) {
      peh[kt] = *(const f16x8*)(sPEh + (w * 16 + c) * 72 + kt * 32 + q * 8);
      pel[kt] = *(const f16x8*)(sPEl + (w * 16 + c) * 72 + kt * 32 + q * 8);
    }
    __syncthreads();                                 // (2) all pe reads done -> sYl writable
    #pragma unroll
    for (int half = 0; half < 2; ++half) {
      f32x4 a1[4], a2[4];
      #pragma unroll
      for (int ht = 0; ht < 4; ++ht) { a1[ht] = (f32x4)0.0f; a2[ht] = (f32x4)0.0f; }
      #pragma unroll
      for (int ht = 0; ht < 4; ++ht) {
        int hT = half * 4 + ht;
        #pragma unroll
        for (int kt = 0; kt < 2; ++kt) {
          f16x8 beh = *(const f16x8*)(wsw + WS_ENC_H + (hT * 2 + kt) * 512 + L * 8);
          f16x8 bel = *(const f16x8*)(wsw + WS_ENC_L + (hT * 2 + kt) * 512 + L * 8);
          a1[ht] = MFMA(beh, peh[kt], a1[ht]);
          a2[ht] = MFMA(bel, peh[kt], a2[ht]);
          a2[ht] = MFMA(beh, pel[kt], a2[ht]);
        }
      }
      #pragma unroll
      for (int ht = 0; ht < 4; ++ht) {
        f32x4 bbv = *(const f32x4*)(b_enc + (half * 4 + ht) * 16 + q * 4);
        #pragma unroll
        for (int r = 0; r < 4; ++r) {
          int hidx = (half * 4 + ht) * 16 + q * 4 + r;
          float v = fmaxf(a1[ht][r] + a2[ht][r] * INV2048 + bbv[r], 0.0f);
          _Float16 h = (_Float16)v;
          sYh[(w * 16 + c) * 136 + hidx] = h;
          sYl[(w * 16 + c) * 136 + hidx] = (_Float16)((v - (float)h) * 2048.0f);
        }
      }
    }
  }
  __syncthreads();                                   // (3) Y complete

  // hoist Y hi frags (64 arch regs)
  f16x8 Ah[4][4];
  #pragma unroll
  for (int nt = 0; nt < 4; ++nt)
    #pragma unroll
    for (int kt = 0; kt < 4; ++kt)
      Ah[nt][kt] = *(const f16x8*)(sYh + (nt * 16 + c) * 136 + kt * 32 + q * 8);
  const f32x4 wsv0 = *(const f32x4*)(w_sig + (2 * w) * 16 + q * 4);
  const f32x4 wsv1 = *(const f32x4*)(w_sig + (2 * w + 1) * 16 + q * 4);
  const float bs = b_sig[0];

  // ---- pass 1: 16-step (e,i) pipeline, HI-ONLY, dbuf weights ----
  float psum[4] = {0.f, 0.f, 0.f, 0.f};

  auto LOADW = [&](int s, f16x8 bh[4], f32x4& bb) {
    int e = s >> 1, i = s & 1;
    int tbase = (e * 8 + 2 * w + i) * 4;
    #pragma unroll
    for (int kt = 0; kt < 4; ++kt)
      bh[kt] = *(const f16x8*)(wsw + WS_SH_H + (tbase + kt) * 512 + L * 8);
    bb = *(const f32x4*)(b_sh + e * 128 + (2 * w + i) * 16 + q * 4);
  };

  auto STEP = [&](int s, const f16x8 bh[4], const f32x4& bb) {
    f32x4 a1[4];
    #pragma unroll
    for (int nt = 0; nt < 4; ++nt) a1[nt] = (f32x4)0.0f;
    #pragma unroll
    for (int kt = 0; kt < 4; ++kt)
      #pragma unroll
      for (int nt = 0; nt < 4; ++nt)
        a1[nt] = MFMA(bh[kt], Ah[nt][kt], a1[nt]);
    f32x4 wv = (s & 1) ? wsv1 : wsv0;
    #pragma unroll
    for (int nt = 0; nt < 4; ++nt)
      #pragma unroll
      for (int r = 0; r < 4; ++r) {
        float sv = fmaxf(a1[nt][r] + bb[r], 0.0f);
        psum[nt] = fmaf(sv, wv[r], psum[nt]);
      }
    if (s & 1) {
      int e = s >> 1;
      #pragma unroll
      for (int nt = 0; nt < 4; ++nt) {
        float v = psum[nt];
        v += __shfl_xor(v, 16);
        v += __shfl_xor(v, 32);
        if (q == 0) sRedE[e * 256 + w * 64 + nt * 16 + c] = v;
        psum[nt] = 0.f;
      }
    }
  };

  {
    f16x8 bh0[4], bh1[4];
    f32x4 bb0, bb1;
    LOADW(0, bh0, bb0);
    #pragma unroll
    for (int s = 0; s < 16; ++s) {
      if ((s & 1) == 0) {
        if (s + 1 < 16) LOADW(s + 1, bh1, bb1);
        STEP(s, bh0, bb0);
      } else {
        if (s + 1 < 16) LOADW(s + 1, bh0, bb0);
        STEP(s, bh1, bb1);
      }
    }
  }
  __syncthreads();                                   // (4)

  // ---- argmax (4 threads/pt x 2 experts) with top-2 gap flagging ----
  {
    int pt = t >> 2;
    int eb = (t & 3) * 2;
    float s_[2], sg_[2];
    #pragma unroll
    for (int j = 0; j < 2; ++j) {
      int e = eb + j;
      const float* rp = sRedE + e * 256 + pt;
      float s = (rp[0] + rp[64]) + (rp[128] + rp[192]);
      float sig = softplus_f(s + bs);
      float z = logf(sig + 1e-10f) / 0.166667f;
      s_[j] = z + gumbel_for((unsigned)((n0 + pt) * 8 + e));
      sg_[j] = sig;
    }
    float T1s, T2s, T1g; int T1i;
    if (s_[1] > s_[0]) { T1s = s_[1]; T1i = eb + 1; T1g = sg_[1]; T2s = s_[0]; }
    else               { T1s = s_[0]; T1i = eb;     T1g = sg_[0]; T2s = s_[1]; }
    #pragma unroll
    for (int m = 1; m <= 2; m <<= 1) {
      float oS = __shfl_xor(T1s, m);
      int   oI = __shfl_xor(T1i, m);
      float oG = __shfl_xor(T1g, m);
      float o2 = __shfl_xor(T2s, m);
      bool ow = (oS > T1s) || (oS == T1s && oI < T1i);
      float n2 = ow ? fmaxf(T1s, o2) : fmaxf(oS, T2s);
      if (ow) { T1s = oS; T1i = oI; T1g = oG; }
      T2s = n2;
    }
    bool flg = (T1s - T2s) < TAU;             // same value on pt's 4 threads
    unsigned long long bl = __ballot(flg);
    unsigned m16 = 0;
    #pragma unroll
    for (int k = 0; k < 16; ++k)
      m16 |= ((unsigned)((bl >> (4 * k)) & 1ull)) << k;
    __syncthreads();                                 // (5) all sRedE reads done
    if ((t & 3) == 0) {                              // provisional (flagged fixed later)
      IBID(pt) = T1i;
      out[(size_t)(n0 + pt) * 4 + 3] = T1g;
    }
    if (L == 0) FMASK(w) = (int)m16;
  }
  __syncthreads();                                   // (6)
  if (t == 0) {
    int n = 0;
    for (int p = 0; p < PT; ++p)
      if ((FMASK(p >> 4) >> (p & 15)) & 1) FLIST(n++) = p;
    FCNT = n;
  }
  __syncthreads();                                   // (7)

  // ---- MFMA-batched exact fixup (3-product) for flagged points ----
  {
    int fcnt = FCNT;                                 // block-uniform
    for (int base = 0; base < fcnt; base += 16) {
      int si = base + c; if (si >= fcnt) si = fcnt - 1;
      int ptf = FLIST(si);
      f16x8 yhb[4], ylb[4];
      #pragma unroll
      for (int kt = 0; kt < 4; ++kt) {
        yhb[kt] = *(const f16x8*)(sYh + ptf * 136 + kt * 32 + q * 8);
        ylb[kt] = *(const f16x8*)(sYl + ptf * 136 + kt * 32 + q * 8);
      }
      #pragma unroll
      for (int j = 0; j < 2; ++j) {
        int e = 2 * w + j;
        float ps = 0.0f;
        #pragma unroll
        for (int jt = 0; jt < 8; ++jt) {
          f32x4 a1 = (f32x4)0.0f, a2 = (f32x4)0.0f;
          #pragma unroll
          for (int kt = 0; kt < 4; ++kt) {
            int tile = (e * 8 + jt) * 4 + kt;
            f16x8 wh = *(const f16x8*)(wsw + WS_SH_H + tile * 512 + L * 8);
            f16x8 wl = *(const f16x8*)(wsw + WS_SH_L + tile * 512 + L * 8);
            a1 = MFMA(wh, yhb[kt], a1);
            a2 = MFMA(wl, yhb[kt], a2);
            a2 = MFMA(wh, ylb[kt], a2);
          }
          f32x4 bb = *(const f32x4*)(b_sh + e * 128 + jt * 16 + q * 4);
          f32x4 wg = *(const f32x4*)(w_sig + jt * 16 + q * 4);
          #pragma unroll
          for (int r = 0; r < 4; ++r) {
            float sv = fmaxf(fmaf(a2[r], INV2048, a1[r]) + bb[r], 0.0f);
            ps = fmaf(sv, wg[r], ps);
          }
        }
        ps += __shfl_xor(ps, 16);
        ps += __shfl_xor(ps, 32);
        if (q == 0) sFix[c * 8 + e] = ps;
      }
      __syncthreads();                               // sFix ready
      if (t < 16 && base + t < fcnt) {
        int pt2 = FLIST(base + t);
        float best = 0.f, bsg = 0.f; int bid = 0;
        #pragma unroll
        for (int e = 0; e < 8; ++e) {
          float sig = softplus_f(sFix[t * 8 + e] + bs);
          float z = logf(sig + 1e-10f) / 0.166667f;
          float score = z + gumbel_for((unsigned)((n0 + pt2) * 8 + e));
          if (e == 0 || score > best) { best = score; bsg = sig; bid = e; }
        }
        IBID(pt2) = bid;
        out[(size_t)(n0 + pt2) * 4 + 3] = bsg;
      }
      __syncthreads();                               // before next batch / buckets
    }
  }

  // ---- bucket lists ----
  if (t < 8) {
    int cnt = 0;
    for (int p = 0; p < PT; ++p) cnt += (IBID(p) == t);
    ICNT(t) = cnt;
  }
  __syncthreads();                                   // (8)
  if (t < 8) {
    int off = 0;
    for (int i = 0; i < t; ++i) off += ICNT(i);
    IOFF(t) = off;
    int k = off;
    for (int p = 0; p < PT; ++p) if (IBID(p) == t) { ILIST(k) = p; k++; }
  }
  __syncthreads();                                   // (9)

  // ---- pass 2a: viewdir PE into sSB + winner S recompute (hi-only) ----
  for (int idx = t; idx < PT * 32; idx += NTH) {
    int s = idx >> 5, cc = idx & 31;
    int pt = ILIST(s);
    const float* xr = x + (size_t)(n0 + pt) * 6 + 3;
    float v;
    if (cc < 3)       v = xr[cc];
    else if (cc < 15) { int g = cc - 3;  v = sinf(xr[g % 3] * (float)(1 << (g / 3))); }
    else if (cc < 27) { int g = cc - 15; v = cosf(xr[g % 3] * (float)(1 << (g / 3))); }
    else              v = 0.0f;
    sSB[s * 168 + 128 + cc] = (_Float16)v;
  }
  #pragma unroll 1
  for (int ei = 0; ei < 2; ++ei) {
    int e = 2 * w + ei;
    int cnt = ICNT(e), off = IOFF(e);
    for (int base = 0; base < cnt; base += 16) {
      int sidx = base + c; if (sidx >= cnt) sidx = cnt - 1;
      int pt = ILIST(off + sidx);
      f16x8 yb[4];
      #pragma unroll
      for (int kt = 0; kt < 4; ++kt)
        yb[kt] = *(const f16x8*)(sYh + pt * 136 + kt * 32 + q * 8);
      f32x4 acc[8];
      #pragma unroll
      for (int jt = 0; jt < 8; ++jt) acc[jt] = (f32x4)0.0f;
      #pragma unroll
      for (int jt = 0; jt < 8; ++jt)
        #pragma unroll
        for (int kt = 0; kt < 4; ++kt) {
          f16x8 a = *(const f16x8*)(wsw + WS_SH_H + ((e * 8 + jt) * 4 + kt) * 512 + L * 8);
          acc[jt] = MFMA(a, yb[kt], acc[jt]);
        }
      bool wr = (base + c) < cnt;
      int slot = off + base + c;
      #pragma unroll
      for (int jt = 0; jt < 8; ++jt) {
        f32x4 bb = *(const f32x4*)(b_sh + e * 128 + jt * 16 + q * 4);
        f16x4 v;
        #pragma unroll
        for (int r = 0; r < 4; ++r)
          v[r] = (_Float16)fmaxf(acc[jt][r] + bb[r], 0.0f);
        if (wr) *(f16x4*)(sSB + slot * 168 + jt * 16 + q * 4) = v;
      }
    }
  }
  __syncthreads();                                   // (10) sYh dead -> sH writable

  // ---- pass 2b: rgb layer 1 via MFMA ([S;vd] @ W_r1) ----
  #pragma unroll 1
  for (int ei = 0; ei < 2; ++ei) {
    int e = 2 * w + ei;
    int cnt = ICNT(e), off = IOFF(e);
    for (int base = 0; base < cnt; base += 16) {
      int sidx = base + c; if (sidx >= cnt) sidx = cnt - 1;
      int slot = off + sidx;
      f16x8 ag[5];
      #pragma unroll
      for (int kt = 0; kt < 5; ++kt)
        ag[kt] = *(const f16x8*)(sSB + slot * 168 + kt * 32 + q * 8);
      f32x4 hacc[4];
      #pragma unroll
      for (int nt = 0; nt < 4; ++nt) hacc[nt] = (f32x4)0.0f;
      #pragma unroll
      for (int nt = 0; nt < 4; ++nt)
        #pragma unroll
        for (int kt = 0; kt < 5; ++kt) {
          f16x8 bf = *(const f16x8*)(wsw + WS_R1_H + ((e * 4 + nt) * 5 + kt) * 512 + L * 8);
          hacc[nt] = MFMA(ag[kt], bf, hacc[nt]);
        }
      #pragma unroll
      for (int nt = 0; nt < 4; ++nt) {
        float bb = b_r1[e * 64 + nt * 16 + c];
        #pragma unroll
        for (int r = 0; r < 4; ++r) {
          int m = q * 4 + r;
          if (base + m < cnt)
            sH[(off + base + m) * 68 + nt * 16 + c] = fmaxf(hacc[nt][r] + bb, 0.0f);
        }
      }
    }
  }
  __syncthreads();                                   // (11)

  // ---- layer 2: rgb = sigmoid(h @ W_r2 + b) ----
  if (t < 192) {
    int s = t / 3, o = t - s * 3;
    int pt = ILIST(s);
    int e = IBID(pt);
    float a = b_r2[e * 3 + o];
    const float* w2 = W_r2 + e * 192 + o;
    #pragma unroll
    for (int jj = 0; jj < 64; jj += 4) {
      f32x4 h4 = *(const f32x4*)(sH + s * 68 + jj);
      a = fmaf(h4.x, w2[jj * 3], a);
      a = fmaf(h4.y, w2[jj * 3 + 3], a);
      a = fmaf(h4.z, w2[jj * 3 + 6], a);
      a = fmaf(h4.w, w2[jj * 3 + 9], a);
    }
    out[(size_t)(n0 + pt) * 4 + o] = 1.0f / (1.0f + expf(-a));
  }
#undef IBID
#undef ILIST
#undef ICNT
#undef IOFF
#undef FMASK
#undef FCNT
#undef FLIST
}

extern "C" void kernel_launch(void* const* d_in, const int* in_sizes, int n_in,
                              void* d_out, int out_size, void* d_ws, size_t ws_size,
                              hipStream_t stream) {
  (void)in_sizes; (void)n_in; (void)ws_size; (void)out_size;
  const float* x     = (const float*)d_in[0];
  const float* W_enc = (const float*)d_in[1];
  const float* b_enc = (const float*)d_in[2];
  const float* W_sh  = (const float*)d_in[3];
  const float* b_sh  = (const float*)d_in[4];
  const float* w_sig = (const float*)d_in[5];
  const float* b_sig = (const float*)d_in[6];
  const float* W_r1  = (const float*)d_in[7];
  const float* b_r1  = (const float*)d_in[8];
  const float* W_r2  = (const float*)d_in[9];
  const float* b_r2  = (const float*)d_in[10];
  _Float16* ws = (_Float16*)d_ws;     // needs 720896 B
  float* outp = (float*)d_out;
  prep_kernel<<<864, 256, 0, stream>>>(W_enc, W_sh, W_r1, ws);
  nerf_moe_kernel<<<NBLK, NTH, 0, stream>>>(x, b_enc, b_sh, w_sig, b_sig,
                                            b_r1, W_r2, b_r2, ws, outp);
}

// Round 12
// 279.596 us; speedup vs baseline: 1.8984x; 1.8984x over previous
//
#include <hip/hip_runtime.h>
#include <hip/hip_bf16.h>

// ---------------------------------------------------------------------------
// GumbelNeRF fused kernel, round 12: R7 + 32-acc transposed phase A.
//
// Theory: occupancy = floor(512/(arch+AGPR)) waves/SIMD; rocprof shows arch
// only. R7 = 124 arch + 64 acc (phase A) = 188 -> 2 waves/SIMD (21.6% ✓).
// Kernel-wide acc max is set solely by phase A; swapping in the transposed
// wave-private phase A (32 acc, proven correct+spill-free in R10) gives
// ~124+32 = 156 <= 170 -> HW grants 3 waves/SIMD naturally. NOTHING else
// changed vs R7 (233us, passing): 3-product pass 1, distributed argmax
// with inline gumbel, bucketed pass 2, LDS 47104 proven layout.
// launch_bounds stays (256,2) — forcing min-3 provably spills (R4/R8/R9).
// ---------------------------------------------------------------------------

#define NPTS 131072
#define PT 64
#define NTH 256
#define NBLK (NPTS / PT)
#define INV2048 (1.0f / 2048.0f)

// ws sections (f16 element offsets) — identical to rounds 2-7
#define WS_ENC_H 0
#define WS_ENC_L 8192
#define WS_SH_H  16384
#define WS_SH_L  147456
#define WS_R1_H  278528

// LDS byte offsets, total 47104
#define OFF_YH   0      // sYh [64][136] f16 = 17408 ; pass2b+: sH [64][68] f32
#define OFF_B    17408  // sPEh[64][72](9216)+sPEl(9216) | sYl[64][136] | sSB[64][168] f16 (21504)
#define OFF_RED  38912  // sRedE [8][4][64] f32 = 8192
#define SMEM_SZ  47104

// smalls live in sSB row-pad (cols 160..167 = bytes 320..335 of each 336B row)
#define S_LIST(s) (*(int*)(smem + OFF_B + (s) * 336 + 320))
#define S_BID(p)  (*(int*)(smem + OFF_B + (p) * 336 + 324))
#define S_CNT(e)  (*(int*)(smem + OFF_B + (e) * 336 + 328))
#define S_OFF(e)  (*(int*)(smem + OFF_B + (e) * 336 + 332))

typedef __attribute__((ext_vector_type(8))) _Float16 f16x8;
typedef __attribute__((ext_vector_type(4))) _Float16 f16x4;
typedef __attribute__((ext_vector_type(4))) float f32x4;

#define MFMA(a, b, c) __builtin_amdgcn_mfma_f32_16x16x32_f16((a), (b), (c), 0, 0, 0)

__device__ __forceinline__ unsigned rotl32(unsigned x, int d) {
  return (x << d) | (x >> (32 - d));
}

// JAX threefry2x32, keys (0,42), counter (0, flat), partitionable fold.
__device__ __forceinline__ float gumbel_for(unsigned flat) {
  const unsigned k0 = 0u, k1 = 42u;
  const unsigned ks2 = k0 ^ k1 ^ 0x1BD11BDAu;
  unsigned x0 = 0u + k0;
  unsigned x1 = flat + k1;
#define TF_RND(r) { x0 += x1; x1 = rotl32(x1, r); x1 ^= x0; }
  TF_RND(13) TF_RND(15) TF_RND(26) TF_RND(6)
  x0 += k1;  x1 += ks2 + 1u;
  TF_RND(17) TF_RND(29) TF_RND(16) TF_RND(24)
  x0 += ks2; x1 += k0 + 2u;
  TF_RND(13) TF_RND(15) TF_RND(26) TF_RND(6)
  x0 += k0;  x1 += k1 + 3u;
  TF_RND(17) TF_RND(29) TF_RND(16) TF_RND(24)
  x0 += k1;  x1 += ks2 + 4u;
  TF_RND(13) TF_RND(15) TF_RND(26) TF_RND(6)
  x0 += ks2; x1 += k0 + 5u;
#undef TF_RND
  unsigned bits = x0 ^ x1;
  float u = __uint_as_float((bits >> 9) | 0x3f800000u) - 1.0f;
  return -logf(-logf(u + 1e-20f) + 1e-20f);
}

// ---------------------------------------------------------------------------
// prep: fp32 weights -> fragment-linear f16 (scaled split) in ws  [unchanged]
// ---------------------------------------------------------------------------
__global__ void prep_kernel(const float* __restrict__ W_enc,
                            const float* __restrict__ W_sh,
                            const float* __restrict__ W_r1,
                            _Float16* __restrict__ ws) {
  int idx = blockIdx.x * 256 + threadIdx.x;
  if (idx < 8192) {
    int tile = idx >> 9, r = idx & 511;
    int L = r >> 3, j = r & 7;
    int nt = tile >> 1, kt = tile & 1;
    int k = kt * 32 + (L >> 4) * 8 + j;
    int n = nt * 16 + (L & 15);
    float v = (k < 63) ? W_enc[k * 128 + n] : 0.0f;
    _Float16 h = (_Float16)v;
    ws[WS_ENC_H + idx] = h;
    ws[WS_ENC_L + idx] = (_Float16)((v - (float)h) * 2048.0f);
  } else if (idx < 8192 + 131072) {
    int s = idx - 8192;
    int tile = s >> 9, r = s & 511;
    int L = r >> 3, j = r & 7;
    int e = tile >> 5, nt = (tile >> 2) & 7, kt = tile & 3;
    int k = kt * 32 + (L >> 4) * 8 + j;
    int n = nt * 16 + (L & 15);
    float v = W_sh[e * 16384 + k * 128 + n];
    _Float16 h = (_Float16)v;
    ws[WS_SH_H + s] = h;
    ws[WS_SH_L + s] = (_Float16)((v - (float)h) * 2048.0f);
  } else if (idx < 8192 + 131072 + 81920) {
    int s = idx - (8192 + 131072);
    int tile = s >> 9, r = s & 511;
    int L = r >> 3, j = r & 7;
    int e = tile / 20, rr = tile % 20;
    int nt = rr / 5, kt = rr % 5;
    int k = kt * 32 + (L >> 4) * 8 + j;
    int n = nt * 16 + (L & 15);
    float v = (k < 155) ? W_r1[e * 9920 + k * 64 + n] : 0.0f;
    ws[WS_R1_H + s] = (_Float16)v;
  }
}

// ---------------------------------------------------------------------------
__global__ __launch_bounds__(NTH, 2)
void nerf_moe_kernel(const float* __restrict__ x,
                     const float* __restrict__ b_enc,
                     const float* __restrict__ b_sh,
                     const float* __restrict__ w_sig, const float* __restrict__ b_sig,
                     const float* __restrict__ b_r1,
                     const float* __restrict__ W_r2,  const float* __restrict__ b_r2,
                     const _Float16* __restrict__ wsw,
                     float* __restrict__ out) {
  __shared__ __align__(16) unsigned char smem[SMEM_SZ];
  _Float16* sYh  = (_Float16*)(smem + OFF_YH);
  float*    sH   = (float*)(smem + OFF_YH);
  _Float16* sYl  = (_Float16*)(smem + OFF_B);
  _Float16* sPEh = (_Float16*)(smem + OFF_B);
  _Float16* sPEl = (_Float16*)(smem + OFF_B + 9216);
  _Float16* sSB  = (_Float16*)(smem + OFF_B);
  float*    sRedE = (float*)(smem + OFF_RED);   // [8][4][64]

  const int t  = threadIdx.x;
  const int w  = t >> 6;        // wave id 0..3
  const int L  = t & 63;        // lane
  const int q  = L >> 4;        // quad 0..3
  const int c  = L & 15;
  const int n0 = blockIdx.x * PT;

  // ---- phase 0: xyz positional encoding ----
  for (int idx = t; idx < PT * 64; idx += NTH) {
    int p = idx >> 6, f = idx & 63;
    const float* xr = x + (size_t)(n0 + p) * 6;
    float v;
    if (f < 3)       v = xr[f];
    else if (f < 33) { int g = f - 3;  v = sinf(xr[g % 3] * (float)(1 << (g / 3))); }
    else if (f < 63) { int g = f - 33; v = cosf(xr[g % 3] * (float)(1 << (g / 3))); }
    else             v = 0.0f;
    _Float16 h = (_Float16)v;
    sPEh[p * 72 + f] = h;
    sPEl[p * 72 + f] = (_Float16)((v - (float)h) * 2048.0f);
  }
  __syncthreads();                                   // (1)

  // ---- phase A (transposed, wave-private pt-tiles; 32 acc max) ----
  {
    f16x8 peh[2], pel[2];
    #pragma unroll
    for (int kt = 0; kt < 2; ++kt) {
      peh[kt] = *(const f16x8*)(sPEh + (w * 16 + c) * 72 + kt * 32 + q * 8);
      pel[kt] = *(const f16x8*)(sPEl + (w * 16 + c) * 72 + kt * 32 + q * 8);
    }
    __syncthreads();                                 // (2) all pe reads done -> sYl writable
    #pragma unroll
    for (int half = 0; half < 2; ++half) {
      f32x4 a1[4], a2[4];
      #pragma unroll
      for (int ht = 0; ht < 4; ++ht) { a1[ht] = (f32x4)0.0f; a2[ht] = (f32x4)0.0f; }
      #pragma unroll
      for (int ht = 0; ht < 4; ++ht) {
        int hT = half * 4 + ht;
        #pragma unroll
        for (int kt = 0; kt < 2; ++kt) {
          f16x8 beh = *(const f16x8*)(wsw + WS_ENC_H + (hT * 2 + kt) * 512 + L * 8);
          f16x8 bel = *(const f16x8*)(wsw + WS_ENC_L + (hT * 2 + kt) * 512 + L * 8);
          a1[ht] = MFMA(beh, peh[kt], a1[ht]);
          a2[ht] = MFMA(bel, peh[kt], a2[ht]);
          a2[ht] = MFMA(beh, pel[kt], a2[ht]);
        }
      }
      #pragma unroll
      for (int ht = 0; ht < 4; ++ht) {
        f32x4 bbv = *(const f32x4*)(b_enc + (half * 4 + ht) * 16 + q * 4);
        #pragma unroll
        for (int r = 0; r < 4; ++r) {
          int hidx = (half * 4 + ht) * 16 + q * 4 + r;
          float v = fmaxf(a1[ht][r] + a2[ht][r] * INV2048 + bbv[r], 0.0f);
          _Float16 h = (_Float16)v;
          sYh[(w * 16 + c) * 136 + hidx] = h;
          sYl[(w * 16 + c) * 136 + hidx] = (_Float16)((v - (float)h) * 2048.0f);
        }
      }
    }
  }
  __syncthreads();                                   // (3) Y complete

  // hoist Y hi frags (64 arch regs); lo re-read from sYl per use
  f16x8 Ah[4][4];
  #pragma unroll
  for (int nt = 0; nt < 4; ++nt)
    #pragma unroll
    for (int kt = 0; kt < 4; ++kt)
      Ah[nt][kt] = *(const f16x8*)(sYh + (nt * 16 + c) * 136 + kt * 32 + q * 8);
  const f32x4 wsv0 = *(const f32x4*)(w_sig + (2 * w) * 16 + q * 4);
  const f32x4 wsv1 = *(const f32x4*)(w_sig + (2 * w + 1) * 16 + q * 4);

  // ---- pass 1: 16-step (e,i) pipeline, 3-product, dbuf weights ----
  float psum[4] = {0.f, 0.f, 0.f, 0.f};

  auto LOADW = [&](int s, f16x8 bh[4], f16x8 bl[4], f32x4& bb) {
    int e = s >> 1, i = s & 1;
    int tbase = (e * 8 + 2 * w + i) * 4;
    #pragma unroll
    for (int kt = 0; kt < 4; ++kt) {
      bh[kt] = *(const f16x8*)(wsw + WS_SH_H + (tbase + kt) * 512 + L * 8);
      bl[kt] = *(const f16x8*)(wsw + WS_SH_L + (tbase + kt) * 512 + L * 8);
    }
    bb = *(const f32x4*)(b_sh + e * 128 + (2 * w + i) * 16 + q * 4);
  };

  auto STEP = [&](int s, const f16x8 bh[4], const f16x8 bl[4], const f32x4& bb) {
    f32x4 a1[4], a2[4];
    #pragma unroll
    for (int nt = 0; nt < 4; ++nt) { a1[nt] = (f32x4)0.0f; a2[nt] = (f32x4)0.0f; }
    #pragma unroll
    for (int kt = 0; kt < 4; ++kt)
      #pragma unroll
      for (int nt = 0; nt < 4; ++nt) {
        f16x8 al = *(const f16x8*)(sYl + (nt * 16 + c) * 136 + kt * 32 + q * 8);
        a1[nt] = MFMA(bh[kt], Ah[nt][kt], a1[nt]);
        a2[nt] = MFMA(bl[kt], Ah[nt][kt], a2[nt]);
        a2[nt] = MFMA(bh[kt], al, a2[nt]);
      }
    f32x4 wv = (s & 1) ? wsv1 : wsv0;
    #pragma unroll
    for (int nt = 0; nt < 4; ++nt)
      #pragma unroll
      for (int r = 0; r < 4; ++r) {
        float sv = fmaxf(fmaf(a2[nt][r], INV2048, a1[nt][r]) + bb[r], 0.0f);
        psum[nt] = fmaf(sv, wv[r], psum[nt]);
      }
    if (s & 1) {                       // end of expert e = s>>1
      int e = s >> 1;
      #pragma unroll
      for (int nt = 0; nt < 4; ++nt) {
        float v = psum[nt];
        v += __shfl_xor(v, 16);
        v += __shfl_xor(v, 32);
        if (q == 0) sRedE[e * 256 + w * 64 + nt * 16 + c] = v;
        psum[nt] = 0.f;
      }
    }
  };

  {
    f16x8 bh0[4], bl0[4], bh1[4], bl1[4];
    f32x4 bb0, bb1;
    LOADW(0, bh0, bl0, bb0);
    #pragma unroll
    for (int s = 0; s < 16; ++s) {
      if ((s & 1) == 0) {
        if (s + 1 < 16) LOADW(s + 1, bh1, bl1, bb1);
        STEP(s, bh0, bl0, bb0);
      } else {
        if (s + 1 < 16) LOADW(s + 1, bh0, bl0, bb0);
        STEP(s, bh1, bl1, bb1);
      }
    }
  }
  __syncthreads();                                   // (4) — only pass-1 barrier

  // ---- argmax: distributed, 4 threads/point x 2 experts, gumbel inline ----
  {
    int pt = t >> 2;
    int eb = (t & 3) * 2;
    float best = -1e30f, bsig = 0.0f;
    int bide = 0;
    const float bs = b_sig[0];
    #pragma unroll
    for (int j = 0; j < 2; ++j) {
      int e = eb + j;
      const float* rp = sRedE + e * 256 + pt;
      float s = (rp[0] + rp[64]) + (rp[128] + rp[192]);
      float dotv = s + bs;
      float sig = fmaxf(dotv, 0.0f) + log1pf(expf(-fabsf(dotv)));
      float z = logf(sig + 1e-10f) / 0.166667f;
      float score = z + gumbel_for((unsigned)((n0 + pt) * 8 + e));
      if (score > best) { best = score; bsig = sig; bide = e; }
    }
    #pragma unroll
    for (int m = 1; m <= 2; m <<= 1) {
      float oS  = __shfl_xor(best, m);
      float oSg = __shfl_xor(bsig, m);
      int   oI  = __shfl_xor(bide, m);
      if (oS > best || (oS == best && oI < bide)) { best = oS; bsig = oSg; bide = oI; }
    }
    if ((t & 3) == 0) {
      S_BID(pt) = bide;                // row-pad slot; sYl dead, sSB not yet
      out[(size_t)(n0 + pt) * 4 + 3] = bsig;
    }
  }
  __syncthreads();                                   // (5)

  // ---- bucket lists ----
  if (t < 8) {
    int cnt = 0;
    for (int p = 0; p < PT; ++p) cnt += (S_BID(p) == t);
    S_CNT(t) = cnt;
  }
  __syncthreads();                                   // (6)
  if (t < 8) {
    int off = 0;
    for (int i = 0; i < t; ++i) off += S_CNT(i);
    S_OFF(t) = off;
    int k = off;
    for (int p = 0; p < PT; ++p) if (S_BID(p) == t) { S_LIST(k) = p; k++; }
  }
  __syncthreads();                                   // (7)

  // ---- pass 2a: viewdir PE into sSB + winner S recompute (transposed) ----
  for (int idx = t; idx < PT * 32; idx += NTH) {
    int s = idx >> 5, cc = idx & 31;
    int pt = S_LIST(s);
    const float* xr = x + (size_t)(n0 + pt) * 6 + 3;
    float v;
    if (cc < 3)       v = xr[cc];
    else if (cc < 15) { int g = cc - 3;  v = sinf(xr[g % 3] * (float)(1 << (g / 3))); }
    else if (cc < 27) { int g = cc - 15; v = cosf(xr[g % 3] * (float)(1 << (g / 3))); }
    else              v = 0.0f;
    sSB[s * 168 + 128 + cc] = (_Float16)v;
  }
  #pragma unroll 1
  for (int ei = 0; ei < 2; ++ei) {
    int e = 2 * w + ei;
    int cnt = S_CNT(e), off = S_OFF(e);
    for (int base = 0; base < cnt; base += 16) {
      int sidx = base + c; if (sidx >= cnt) sidx = cnt - 1;
      int pt = S_LIST(off + sidx);
      f16x8 yb[4];
      #pragma unroll
      for (int kt = 0; kt < 4; ++kt)
        yb[kt] = *(const f16x8*)(sYh + pt * 136 + kt * 32 + q * 8);
      f32x4 acc[8];
      #pragma unroll
      for (int jt = 0; jt < 8; ++jt) acc[jt] = (f32x4)0.0f;
      #pragma unroll
      for (int jt = 0; jt < 8; ++jt)
        #pragma unroll
        for (int kt = 0; kt < 4; ++kt) {
          f16x8 a = *(const f16x8*)(wsw + WS_SH_H + ((e * 8 + jt) * 4 + kt) * 512 + L * 8);
          acc[jt] = MFMA(a, yb[kt], acc[jt]);
        }
      bool wr = (base + c) < cnt;
      int slot = off + base + c;
      #pragma unroll
      for (int jt = 0; jt < 8; ++jt) {
        f32x4 bb = *(const f32x4*)(b_sh + e * 128 + jt * 16 + q * 4);
        f16x4 v;
        #pragma unroll
        for (int r = 0; r < 4; ++r)
          v[r] = (_Float16)fmaxf(acc[jt][r] + bb[r], 0.0f);
        if (wr) *(f16x4*)(sSB + slot * 168 + jt * 16 + q * 4) = v;
      }
    }
  }
  __syncthreads();                                   // (8) sYh dead -> sH writable

  // ---- pass 2b: rgb layer 1 via MFMA ([S;vd] @ W_r1) ----
  #pragma unroll 1
  for (int ei = 0; ei < 2; ++ei) {
    int e = 2 * w + ei;
    int cnt = S_CNT(e), off = S_OFF(e);
    for (int base = 0; base < cnt; base += 16) {
      int sidx = base + c; if (sidx >= cnt) sidx = cnt - 1;
      int slot = off + sidx;
      f16x8 ag[5];
      #pragma unroll
      for (int kt = 0; kt < 5; ++kt)
        ag[kt] = *(const f16x8*)(sSB + slot * 168 + kt * 32 + q * 8);
      f32x4 hacc[4];
      #pragma unroll
      for (int nt = 0; nt < 4; ++nt) hacc[nt] = (f32x4)0.0f;
      #pragma unroll
      for (int nt = 0; nt < 4; ++nt)
        #pragma unroll
        for (int kt = 0; kt < 5; ++kt) {
          f16x8 bf = *(const f16x8*)(wsw + WS_R1_H + ((e * 4 + nt) * 5 + kt) * 512 + L * 8);
          hacc[nt] = MFMA(ag[kt], bf, hacc[nt]);
        }
      #pragma unroll
      for (int nt = 0; nt < 4; ++nt) {
        float bb = b_r1[e * 64 + nt * 16 + c];
        #pragma unroll
        for (int r = 0; r < 4; ++r) {
          int m = q * 4 + r;
          if (base + m < cnt)
            sH[(off + base + m) * 68 + nt * 16 + c] = fmaxf(hacc[nt][r] + bb, 0.0f);
        }
      }
    }
  }
  __syncthreads();                                   // (9)

  // ---- layer 2: rgb = sigmoid(h @ W_r2 + b) ----
  if (t < 192) {
    int s = t / 3, o = t - s * 3;
    int pt = S_LIST(s);
    int e = S_BID(pt);
    float a = b_r2[e * 3 + o];
    const float* w2 = W_r2 + e * 192 + o;
    #pragma unroll
    for (int jj = 0; jj < 64; jj += 4) {
      f32x4 h4 = *(const f32x4*)(sH + s * 68 + jj);
      a = fmaf(h4.x, w2[jj * 3], a);
      a = fmaf(h4.y, w2[jj * 3 + 3], a);
      a = fmaf(h4.z, w2[jj * 3 + 6], a);
      a = fmaf(h4.w, w2[jj * 3 + 9], a);
    }
    out[(size_t)(n0 + pt) * 4 + o] = 1.0f / (1.0f + expf(-a));
  }
}

extern "C" void kernel_launch(void* const* d_in, const int* in_sizes, int n_in,
                              void* d_out, int out_size, void* d_ws, size_t ws_size,
                              hipStream_t stream) {
  (void)in_sizes; (void)n_in; (void)ws_size; (void)out_size;
  const float* x     = (const float*)d_in[0];
  const float* W_enc = (const float*)d_in[1];
  const float* b_enc = (const float*)d_in[2];
  const float* W_sh  = (const float*)d_in[3];
  const float* b_sh  = (const float*)d_in[4];
  const float* w_sig = (const float*)d_in[5];
  const float* b_sig = (const float*)d_in[6];
  const float* W_r1  = (const float*)d_in[7];
  const float* b_r1  = (const float*)d_in[8];
  const float* W_r2  = (const float*)d_in[9];
  const float* b_r2  = (const float*)d_in[10];
  _Float16* ws = (_Float16*)d_ws;     // needs 720896 B
  float* outp = (float*)d_out;
  prep_kernel<<<864, 256, 0, stream>>>(W_enc, W_sh, W_r1, ws);
  nerf_moe_kernel<<<NBLK, NTH, 0, stream>>>(x, b_enc, b_sh, w_sig, b_sig,
                                            b_r1, W_r2, b_r2, ws, outp);
}